// Round 1
// baseline (5615.875 us; speedup 1.0000x reference)
//
#include <hip/hip_runtime.h>
#include <hip/hip_fp16.h>
#include <cstdint>
#include <cstddef>

typedef _Float16 half_t;
typedef _Float16 half2_t __attribute__((ext_vector_type(2)));
typedef _Float16 half8_t __attribute__((ext_vector_type(8)));
typedef float    f32x4   __attribute__((ext_vector_type(4)));

#define T_FULL  2048
#define T_CH    512
#define N_CHUNK 4
#define B_SZ    64
#define H_SZ    256
#define G4      1024
#define CH_M    (B_SZ * T_CH)   // 32768

// Whh k-pair (128 pairs total) split: 102 in VGPRs, 14 in LDS (7 quads), 12 streamed (6 quads)
#define KP_RF   102
#define NQ_LDS  7
#define NQ_STR  6

// ---------------- workspace layout (bytes) ----------------
static constexpr size_t OFF_XW   = 0;                      // half [CH_M][1024] repacked (i,f,g,o)x256
static constexpr size_t OFF_H    = OFF_XW   + (size_t)CH_M * G4 * 2;   // half [CH_M][256]
static constexpr size_t OFF_WIH  = OFF_H    + (size_t)CH_M * H_SZ * 2; // half [1024][256]  (B^T)
static constexpr size_t OFF_WOUT = OFF_WIH  + (size_t)G4 * 256 * 2;    // half [256][256]   (B^T)
static constexpr size_t OFF_WHHP = OFF_WOUT + (size_t)256 * 256 * 2;   // uint [128][1024] f16 pairs
static constexpr size_t OFF_WHHL = OFF_WHHP + (size_t)128 * 1024 * 4;  // uint [7*2*256*4] quads
static constexpr size_t OFF_WSTR = OFF_WHHL + (size_t)NQ_LDS * 2048 * 4;// uint [6*2*256*4] quads
static constexpr size_t OFF_SC   = OFF_WSTR + (size_t)NQ_STR * 2048 * 4;// float [64][256]
static constexpr size_t OFF_SH   = OFF_SC   + (size_t)B_SZ * H_SZ * 4; // uint [64][128] f16 pairs

// ---------------- helpers ----------------
__device__ __forceinline__ unsigned int packh2(float a, float b) {
    half2_t h; h.x = (half_t)a; h.y = (half_t)b;
    return __builtin_bit_cast(unsigned int, h);
}

__device__ __forceinline__ float dot2f(unsigned int hp, unsigned int wp, float acc) {
#if __has_builtin(__builtin_amdgcn_fdot2)
    return __builtin_amdgcn_fdot2(__builtin_bit_cast(half2_t, hp),
                                  __builtin_bit_cast(half2_t, wp), acc, false);
#else
    half2_t h = __builtin_bit_cast(half2_t, hp);
    half2_t w = __builtin_bit_cast(half2_t, wp);
    return fmaf((float)h.y, (float)w.y, fmaf((float)h.x, (float)w.x, acc));
#endif
}

__device__ __forceinline__ unsigned int rlane(unsigned int v, int lane) {
    return (unsigned int)__builtin_amdgcn_readlane((int)v, lane);
}

__device__ __forceinline__ float sigm(float x)  { return 1.0f / (1.0f + __expf(-x)); }
__device__ __forceinline__ float tanh_(float x) { return 1.0f - 2.0f / (__expf(2.0f * x) + 1.0f); }

// ---------------- K0: pack weights + init state ----------------
static constexpr int PACK_TOTAL = 262144 + 65536 + 131072
                                + NQ_LDS * 2048 + NQ_STR * 2048 + 16384 + 8192;

__global__ __launch_bounds__(256) void pack_kernel(
    const float* __restrict__ Wih, const float* __restrict__ Whh,
    const float* __restrict__ Wout, const float* __restrict__ c0,
    const float* __restrict__ h0,
    half_t* __restrict__ wih_t, half_t* __restrict__ wout_t,
    unsigned int* __restrict__ whh_pack, unsigned int* __restrict__ whh_ldsq,
    unsigned int* __restrict__ whh_str,
    float* __restrict__ state_c, unsigned int* __restrict__ state_h)
{
    const int stride = gridDim.x * blockDim.x;
    for (int idx = blockIdx.x * blockDim.x + threadIdx.x; idx < PACK_TOTAL; idx += stride) {
        int r = idx;
        if (r < 262144) {                       // wih_t[n][k] = Wih[k][n]
            int n = r >> 8, k = r & 255;
            wih_t[r] = (half_t)Wih[k * 1024 + n];
            continue;
        }
        r -= 262144;
        if (r < 65536) {                        // wout_t[n][k] = Wout[k][n]
            int n = r >> 8, k = r & 255;
            wout_t[r] = (half_t)Wout[k * 256 + n];
            continue;
        }
        r -= 65536;
        if (r < 131072) {                       // whh_pack[kp][j] = (Whh[2kp][j], Whh[2kp+1][j])
            int kp = r >> 10, j = r & 1023;
            whh_pack[r] = packh2(Whh[(2 * kp) * 1024 + j], Whh[(2 * kp + 1) * 1024 + j]);
            continue;
        }
        r -= 131072;
        if (r < NQ_LDS * 2048) {                // LDS quads, k = 204..231
            int w = r & 3, t = (r >> 2) & 255, hh = (r >> 10) & 1, kpq = r >> 11;
            int kb  = 204 + kpq * 4 + ((w >> 1) << 1);
            int col = t + hh * 512 + ((w & 1) << 8);
            whh_ldsq[r] = packh2(Whh[kb * 1024 + col], Whh[(kb + 1) * 1024 + col]);
            continue;
        }
        r -= NQ_LDS * 2048;
        if (r < NQ_STR * 2048) {                // streamed quads, k = 232..255
            int w = r & 3, t = (r >> 2) & 255, hh = (r >> 10) & 1, kq = r >> 11;
            int kb  = 232 + kq * 4 + ((w >> 1) << 1);
            int col = t + hh * 512 + ((w & 1) << 8);
            whh_str[r] = packh2(Whh[kb * 1024 + col], Whh[(kb + 1) * 1024 + col]);
            continue;
        }
        r -= NQ_STR * 2048;
        if (r < 16384) { state_c[r] = c0[r]; continue; }
        r -= 16384;
        state_h[r] = packh2(h0[2 * r], h0[2 * r + 1]);
    }
}

// ---------------- K1/K3: f16 MFMA GEMM, 128x128 tile, K=256 ----------------
// AMODE 1: A = fp32 with chunked row map (x);  AMODE 0: A = f16 contiguous (h_chunk)
// CMODE 0: C = f16, gate-repacked layout [m][(n&255)*4 + n>>8] (xw)
// CMODE 1: C = fp32 with chunked row map + bias (d_out)
template<int AMODE, int CMODE>
__global__ __launch_bounds__(256) void gemm16(
    const void* __restrict__ Ap, const half_t* __restrict__ Bt,
    void* __restrict__ Cp, const float* __restrict__ bias, int chunk0)
{
    __shared__ half_t Als[128][40];
    __shared__ half_t Bls[128][40];
    const int tid  = threadIdx.x;
    const int lane = tid & 63, wid = tid >> 6;
    const int wr = wid >> 1, wc = wid & 1;
    const int m0 = blockIdx.x * 128, n0 = blockIdx.y * 128;

    f32x4 acc[4][4] = {};

    for (int kc = 0; kc < 8; ++kc) {
        __syncthreads();
        if (AMODE == 1) {
            const float* A = (const float*)Ap;
            #pragma unroll
            for (int i = 0; i < 4; ++i) {
                int l = tid + i * 256;
                int row = l >> 3, kq = l & 7;
                int m = m0 + row;
                int arow = ((m >> 9) << 11) + chunk0 + (m & 511);
                f32x4 v = *(const f32x4*)(A + (size_t)arow * 256 + kc * 32 + kq * 4);
                uint2 pk;
                pk.x = packh2(v.x, v.y);
                pk.y = packh2(v.z, v.w);
                *reinterpret_cast<uint2*>(&Als[row][kq * 4]) = pk;
            }
        } else {
            const half_t* A = (const half_t*)Ap;
            #pragma unroll
            for (int i = 0; i < 2; ++i) {
                int l = tid + i * 256;
                int row = l >> 2, ko = l & 3;
                half8_t v = *(const half8_t*)(A + (size_t)(m0 + row) * 256 + kc * 32 + ko * 8);
                *reinterpret_cast<half8_t*>(&Als[row][ko * 8]) = v;
            }
        }
        #pragma unroll
        for (int i = 0; i < 2; ++i) {
            int l = tid + i * 256;
            int row = l >> 2, ko = l & 3;
            half8_t v = *(const half8_t*)(Bt + (size_t)(n0 + row) * 256 + kc * 32 + ko * 8);
            *reinterpret_cast<half8_t*>(&Bls[row][ko * 8]) = v;
        }
        __syncthreads();

        half8_t af[4], bf[4];
        #pragma unroll
        for (int mi = 0; mi < 4; ++mi)
            af[mi] = *reinterpret_cast<const half8_t*>(&Als[wr * 64 + mi * 16 + (lane & 15)][(lane >> 4) * 8]);
        #pragma unroll
        for (int ni = 0; ni < 4; ++ni)
            bf[ni] = *reinterpret_cast<const half8_t*>(&Bls[wc * 64 + ni * 16 + (lane & 15)][(lane >> 4) * 8]);
        #pragma unroll
        for (int mi = 0; mi < 4; ++mi)
            #pragma unroll
            for (int ni = 0; ni < 4; ++ni)
                acc[mi][ni] = __builtin_amdgcn_mfma_f32_16x16x32_f16(af[mi], bf[ni], acc[mi][ni], 0, 0, 0);
    }

    #pragma unroll
    for (int mi = 0; mi < 4; ++mi) {
        #pragma unroll
        for (int ni = 0; ni < 4; ++ni) {
            #pragma unroll
            for (int reg = 0; reg < 4; ++reg) {
                int row = m0 + wr * 64 + mi * 16 + (lane >> 4) * 4 + reg;   // m
                int col = n0 + wc * 64 + ni * 16 + (lane & 15);             // n
                float v = acc[mi][ni][reg] + bias[col];
                if (CMODE == 0) {
                    ((half_t*)Cp)[(size_t)row * 1024 + ((col & 255) << 2) + (col >> 8)] = (half_t)v;
                } else {
                    int crow = ((row >> 9) << 11) + chunk0 + (row & 511);
                    ((float*)Cp)[(size_t)crow * 256 + col] = v;
                }
            }
        }
    }
}

// ---------------- K2: per-chain recurrent LSTM kernel ----------------
__global__ __launch_bounds__(256, 1) void rnn_kernel(
    const unsigned int* __restrict__ whh_pack,
    const uint4* __restrict__ whh_ldsq,
    const uint4* __restrict__ whh_str,
    const half_t* __restrict__ xw,
    half_t* __restrict__ h_out,
    float* __restrict__ state_c,
    unsigned int* __restrict__ state_h)
{
    __shared__ uint4 lds_w[NQ_LDS * 512];        // 57344 B
    __shared__ unsigned int hbuf[128];           // h as f16 pairs

    const int t = threadIdx.x;                   // 0..255: h element / gate column base
    const int b = blockIdx.x;                    // chain
    const int lane = t & 63;

    #pragma unroll
    for (int i = 0; i < NQ_LDS * 2; ++i)
        lds_w[t + i * 256] = whh_ldsq[t + i * 256];
    if (t < 128) hbuf[t] = state_h[b * 128 + t];
    float c = state_c[b * 256 + t];

    // register-resident Whh: k-pairs 0..101 x 4 gate columns {t, 256+t, 512+t, 768+t}
    unsigned int wreg[KP_RF][4];
    #pragma unroll
    for (int kp = 0; kp < KP_RF; ++kp) {
        #pragma unroll
        for (int q = 0; q < 4; ++q)
            wreg[kp][q] = whh_pack[kp * 1024 + q * 256 + t];
    }
    __syncthreads();

    const half_t* xwp = xw + (size_t)b * T_CH * 1024 + t * 4;
    half_t* hop = h_out + (size_t)b * T_CH * 256 + t;

    for (int step = 0; step < T_CH; ++step) {
        unsigned int hv0 = hbuf[lane];
        unsigned int hv1 = hbuf[lane + 64];
        __syncthreads();   // all reads of hbuf done before anyone rewrites it

        // xw already holds x@Wih + bh, repacked as (i,f,g,o) quad per element
        float a0, a1, a2, a3;
        {
            uint2 xv = *(const uint2*)xwp;
            half2_t p0 = __builtin_bit_cast(half2_t, xv.x);
            half2_t p1 = __builtin_bit_cast(half2_t, xv.y);
            a0 = (float)p0.x; a1 = (float)p0.y; a2 = (float)p1.x; a3 = (float)p1.y;
        }

        // RF part: k-pairs 0..101
        #pragma unroll
        for (int kp = 0; kp < KP_RF; ++kp) {
            unsigned int s = rlane((kp < 64) ? hv0 : hv1, kp & 63);
            a0 = dot2f(s, wreg[kp][0], a0);
            a1 = dot2f(s, wreg[kp][1], a1);
            a2 = dot2f(s, wreg[kp][2], a2);
            a3 = dot2f(s, wreg[kp][3], a3);
        }
        // LDS part: k-pairs 102..115 (lanes 38..51 of hv1)
        #pragma unroll
        for (int kpq = 0; kpq < NQ_LDS; ++kpq) {
            uint4 qa = lds_w[kpq * 512 + t];
            uint4 qb = lds_w[kpq * 512 + 256 + t];
            unsigned int s0 = rlane(hv1, 38 + 2 * kpq);
            unsigned int s1 = rlane(hv1, 39 + 2 * kpq);
            a0 = dot2f(s0, qa.x, a0); a1 = dot2f(s0, qa.y, a1);
            a2 = dot2f(s0, qb.x, a2); a3 = dot2f(s0, qb.y, a3);
            a0 = dot2f(s1, qa.z, a0); a1 = dot2f(s1, qa.w, a1);
            a2 = dot2f(s1, qb.z, a2); a3 = dot2f(s1, qb.w, a3);
        }
        // streamed part (L2-hot, 48 KB shared by all WGs): k-pairs 116..127 (lanes 52..63)
        #pragma unroll
        for (int kq = 0; kq < NQ_STR; ++kq) {
            uint4 qa = whh_str[kq * 512 + t];
            uint4 qb = whh_str[kq * 512 + 256 + t];
            unsigned int s0 = rlane(hv1, 52 + 2 * kq);
            unsigned int s1 = rlane(hv1, 53 + 2 * kq);
            a0 = dot2f(s0, qa.x, a0); a1 = dot2f(s0, qa.y, a1);
            a2 = dot2f(s0, qb.x, a2); a3 = dot2f(s0, qb.y, a3);
            a0 = dot2f(s1, qa.z, a0); a1 = dot2f(s1, qa.w, a1);
            a2 = dot2f(s1, qb.z, a2); a3 = dot2f(s1, qb.w, a3);
        }

        // thread-local LSTM cell update (gate order i,f,g,o)
        float ig = sigm(a0), fg = sigm(a1), gg = tanh_(a2), og = sigm(a3);
        c = fg * c + ig * gg;
        float hn = og * tanh_(c);
        half_t h16 = (half_t)hn;
        reinterpret_cast<half_t*>(hbuf)[t] = h16;
        *hop = h16;
        hop += 256;
        xwp += 1024;
        __syncthreads();   // new h visible before next step's reads
    }

    state_c[b * 256 + t] = c;
    if (t < 128) state_h[b * 128 + t] = hbuf[t];
}

// ---------------- launch ----------------
extern "C" void kernel_launch(void* const* d_in, const int* in_sizes, int n_in,
                              void* d_out, int out_size, void* d_ws, size_t ws_size,
                              hipStream_t stream) {
    const float* x    = (const float*)d_in[0];
    const float* c0   = (const float*)d_in[1];
    const float* h0   = (const float*)d_in[2];
    const float* Wih  = (const float*)d_in[3];
    const float* Whh  = (const float*)d_in[4];
    const float* bh   = (const float*)d_in[5];
    const float* Wout = (const float*)d_in[6];
    const float* bout = (const float*)d_in[7];

    char* ws = (char*)d_ws;
    half_t* xw            = (half_t*)(ws + OFF_XW);
    half_t* h_chunk       = (half_t*)(ws + OFF_H);
    half_t* wih_t         = (half_t*)(ws + OFF_WIH);
    half_t* wout_t        = (half_t*)(ws + OFF_WOUT);
    unsigned int* whh_pack = (unsigned int*)(ws + OFF_WHHP);
    unsigned int* whh_ldsq = (unsigned int*)(ws + OFF_WHHL);
    unsigned int* whh_str  = (unsigned int*)(ws + OFF_WSTR);
    float* state_c        = (float*)(ws + OFF_SC);
    unsigned int* state_h = (unsigned int*)(ws + OFF_SH);

    pack_kernel<<<512, 256, 0, stream>>>(Wih, Whh, Wout, c0, h0,
                                         wih_t, wout_t, whh_pack, whh_ldsq, whh_str,
                                         state_c, state_h);

    for (int ch = 0; ch < N_CHUNK; ++ch) {
        int chunk0 = ch * T_CH;
        // xw = x @ Wih + bh for this chunk (f16, gate-repacked)
        gemm16<1, 0><<<dim3(CH_M / 128, G4 / 128), 256, 0, stream>>>(
            (const void*)x, wih_t, (void*)xw, bh, chunk0);
        // sequential LSTM over the chunk
        rnn_kernel<<<B_SZ, 256, 0, stream>>>(whh_pack, (const uint4*)whh_ldsq,
                                             (const uint4*)whh_str, xw, h_chunk,
                                             state_c, state_h);
        // y = h @ Wout + bout for this chunk (fp32 -> d_out)
        gemm16<0, 1><<<dim3(CH_M / 128, H_SZ / 128), 256, 0, stream>>>(
            (const void*)h_chunk, wout_t, d_out, bout, chunk0);
    }
    (void)in_sizes; (void)n_in; (void)out_size; (void)ws_size;
}

// Round 2
// 4087.778 us; speedup vs baseline: 1.3738x; 1.3738x over previous
//
#include <hip/hip_runtime.h>
#include <hip/hip_fp16.h>
#include <cstdint>
#include <cstddef>

typedef _Float16 half_t;
typedef _Float16 half2_t __attribute__((ext_vector_type(2)));
typedef _Float16 half8_t __attribute__((ext_vector_type(8)));
typedef float    f32x4   __attribute__((ext_vector_type(4)));

#define T_FULL  2048
#define T_CH    512
#define N_CHUNK 4
#define B_SZ    64
#define H_SZ    256
#define G4      1024
#define CH_M    (B_SZ * T_CH)   // 32768

// Per hh-half (64 k-pairs): 48 in VGPRs, 7 in LDS, 9 streamed from L2
#define KP_RF   48
#define KP_LDS  7
#define KP_STR  9

// ---------------- workspace layout (bytes) ----------------
static constexpr size_t OFF_XW   = 0;                                   // half [CH_M][1024] (i,f,g,o)x256
static constexpr size_t OFF_H    = OFF_XW   + (size_t)CH_M * G4 * 2;    // half [CH_M][256]
static constexpr size_t OFF_WIH  = OFF_H    + (size_t)CH_M * H_SZ * 2;  // half [1024][256]  (B^T)
static constexpr size_t OFF_WOUT = OFF_WIH  + (size_t)G4 * 256 * 2;     // half [256][256]   (B^T)
static constexpr size_t OFF_WRF  = OFF_WOUT + (size_t)256 * 256 * 2;    // uint [2][48][1024]
static constexpr size_t OFF_WLDS = OFF_WRF  + (size_t)2 * KP_RF * 1024 * 4;  // uint4 [2][7][256]
static constexpr size_t OFF_WSTR = OFF_WLDS + (size_t)2 * KP_LDS * 256 * 16; // uint4 [2][9][256]
static constexpr size_t OFF_SC   = OFF_WSTR + (size_t)2 * KP_STR * 256 * 16; // float [64][256]
static constexpr size_t OFF_SH   = OFF_SC   + (size_t)B_SZ * H_SZ * 4;  // uint [64][128] f16 pairs

// ---------------- helpers ----------------
__device__ __forceinline__ unsigned int packh2(float a, float b) {
    half2_t h; h.x = (half_t)a; h.y = (half_t)b;
    return __builtin_bit_cast(unsigned int, h);
}

__device__ __forceinline__ float dot2f(unsigned int hp, unsigned int wp, float acc) {
#if __has_builtin(__builtin_amdgcn_fdot2)
    return __builtin_amdgcn_fdot2(__builtin_bit_cast(half2_t, hp),
                                  __builtin_bit_cast(half2_t, wp), acc, false);
#else
    half2_t h = __builtin_bit_cast(half2_t, hp);
    half2_t w = __builtin_bit_cast(half2_t, wp);
    return fmaf((float)h.y, (float)w.y, fmaf((float)h.x, (float)w.x, acc));
#endif
}

__device__ __forceinline__ unsigned int rlane(unsigned int v, int lane) {
    return (unsigned int)__builtin_amdgcn_readlane((int)v, lane);
}

__device__ __forceinline__ float sigm(float x)  { return 1.0f / (1.0f + __expf(-x)); }
__device__ __forceinline__ float tanh_(float x) { return 1.0f - 2.0f / (__expf(2.0f * x) + 1.0f); }

// ---------------- K0: pack weights + init state ----------------
// sections: wih 262144 | wout 65536 | rf 98304 | lds 14336 | str 18432 | c 16384 | h 8192
static constexpr int PACK_TOTAL = 262144 + 65536 + 2 * KP_RF * 1024
                                + 2 * KP_LDS * 256 * 4 + 2 * KP_STR * 256 * 4
                                + 16384 + 8192;

__global__ __launch_bounds__(256) void pack_kernel(
    const float* __restrict__ Wih, const float* __restrict__ Whh,
    const float* __restrict__ Wout, const float* __restrict__ c0,
    const float* __restrict__ h0,
    half_t* __restrict__ wih_t, half_t* __restrict__ wout_t,
    unsigned int* __restrict__ whh_rf, unsigned int* __restrict__ whh_lds,
    unsigned int* __restrict__ whh_str,
    float* __restrict__ state_c, unsigned int* __restrict__ state_h)
{
    const int stride = gridDim.x * blockDim.x;
    for (int idx = blockIdx.x * blockDim.x + threadIdx.x; idx < PACK_TOTAL; idx += stride) {
        int r = idx;
        if (r < 262144) {                       // wih_t[n][k] = Wih[k][n]
            int n = r >> 8, k = r & 255;
            wih_t[r] = (half_t)Wih[k * 1024 + n];
            continue;
        }
        r -= 262144;
        if (r < 65536) {                        // wout_t[n][k] = Wout[k][n]
            int n = r >> 8, k = r & 255;
            wout_t[r] = (half_t)Wout[k * 256 + n];
            continue;
        }
        r -= 65536;
        if (r < 2 * KP_RF * 1024) {             // whh_rf[hh][pl][col], p = hh*64+pl, k=2p
            int col = r & 1023, q2 = r >> 10;
            int hh = q2 / KP_RF, pl = q2 % KP_RF;
            int k0 = 2 * (hh * 64 + pl);
            whh_rf[r] = packh2(Whh[k0 * 1024 + col], Whh[(k0 + 1) * 1024 + col]);
            continue;
        }
        r -= 2 * KP_RF * 1024;
        if (r < 2 * KP_LDS * 256 * 4) {         // whh_lds[hh][ql][e].j  col=j*256+e, p=hh*64+48+ql
            int j = r & 3, e = (r >> 2) & 255, rest = r >> 10;
            int ql = rest % KP_LDS, hh = rest / KP_LDS;
            int k0 = 2 * (hh * 64 + KP_RF + ql);
            int col = j * 256 + e;
            whh_lds[r] = packh2(Whh[k0 * 1024 + col], Whh[(k0 + 1) * 1024 + col]);
            continue;
        }
        r -= 2 * KP_LDS * 256 * 4;
        if (r < 2 * KP_STR * 256 * 4) {         // whh_str[hh][sl][e].j  p=hh*64+55+sl
            int j = r & 3, e = (r >> 2) & 255, rest = r >> 10;
            int sl = rest % KP_STR, hh = rest / KP_STR;
            int k0 = 2 * (hh * 64 + KP_RF + KP_LDS + sl);
            int col = j * 256 + e;
            whh_str[r] = packh2(Whh[k0 * 1024 + col], Whh[(k0 + 1) * 1024 + col]);
            continue;
        }
        r -= 2 * KP_STR * 256 * 4;
        if (r < 16384) { state_c[r] = c0[r]; continue; }
        r -= 16384;
        state_h[r] = packh2(h0[2 * r], h0[2 * r + 1]);
    }
}

// ---------------- K1/K3: f16 MFMA GEMM, 128x128 tile, K=256 ----------------
template<int AMODE, int CMODE>
__global__ __launch_bounds__(256) void gemm16(
    const void* __restrict__ Ap, const half_t* __restrict__ Bt,
    void* __restrict__ Cp, const float* __restrict__ bias, int chunk0)
{
    __shared__ half_t Als[128][40];
    __shared__ half_t Bls[128][40];
    const int tid  = threadIdx.x;
    const int lane = tid & 63, wid = tid >> 6;
    const int wr = wid >> 1, wc = wid & 1;
    const int m0 = blockIdx.x * 128, n0 = blockIdx.y * 128;

    f32x4 acc[4][4] = {};

    for (int kc = 0; kc < 8; ++kc) {
        __syncthreads();
        if (AMODE == 1) {
            const float* A = (const float*)Ap;
            #pragma unroll
            for (int i = 0; i < 4; ++i) {
                int l = tid + i * 256;
                int row = l >> 3, kq = l & 7;
                int m = m0 + row;
                int arow = ((m >> 9) << 11) + chunk0 + (m & 511);
                f32x4 v = *(const f32x4*)(A + (size_t)arow * 256 + kc * 32 + kq * 4);
                uint2 pk;
                pk.x = packh2(v.x, v.y);
                pk.y = packh2(v.z, v.w);
                *reinterpret_cast<uint2*>(&Als[row][kq * 4]) = pk;
            }
        } else {
            const half_t* A = (const half_t*)Ap;
            #pragma unroll
            for (int i = 0; i < 2; ++i) {
                int l = tid + i * 256;
                int row = l >> 2, ko = l & 3;
                half8_t v = *(const half8_t*)(A + (size_t)(m0 + row) * 256 + kc * 32 + ko * 8);
                *reinterpret_cast<half8_t*>(&Als[row][ko * 8]) = v;
            }
        }
        #pragma unroll
        for (int i = 0; i < 2; ++i) {
            int l = tid + i * 256;
            int row = l >> 2, ko = l & 3;
            half8_t v = *(const half8_t*)(Bt + (size_t)(n0 + row) * 256 + kc * 32 + ko * 8);
            *reinterpret_cast<half8_t*>(&Bls[row][ko * 8]) = v;
        }
        __syncthreads();

        half8_t af[4], bf[4];
        #pragma unroll
        for (int mi = 0; mi < 4; ++mi)
            af[mi] = *reinterpret_cast<const half8_t*>(&Als[wr * 64 + mi * 16 + (lane & 15)][(lane >> 4) * 8]);
        #pragma unroll
        for (int ni = 0; ni < 4; ++ni)
            bf[ni] = *reinterpret_cast<const half8_t*>(&Bls[wc * 64 + ni * 16 + (lane & 15)][(lane >> 4) * 8]);
        #pragma unroll
        for (int mi = 0; mi < 4; ++mi)
            #pragma unroll
            for (int ni = 0; ni < 4; ++ni)
                acc[mi][ni] = __builtin_amdgcn_mfma_f32_16x16x32_f16(af[mi], bf[ni], acc[mi][ni], 0, 0, 0);
    }

    #pragma unroll
    for (int mi = 0; mi < 4; ++mi) {
        #pragma unroll
        for (int ni = 0; ni < 4; ++ni) {
            #pragma unroll
            for (int reg = 0; reg < 4; ++reg) {
                int row = m0 + wr * 64 + mi * 16 + (lane >> 4) * 4 + reg;   // m
                int col = n0 + wc * 64 + ni * 16 + (lane & 15);             // n
                float v = acc[mi][ni][reg] + bias[col];
                if (CMODE == 0) {
                    ((half_t*)Cp)[(size_t)row * 1024 + ((col & 255) << 2) + (col >> 8)] = (half_t)v;
                } else {
                    int crow = ((row >> 9) << 11) + chunk0 + (row & 511);
                    ((float*)Cp)[(size_t)crow * 256 + col] = v;
                }
            }
        }
    }
}

// ---------------- K2: per-chain recurrent LSTM, K-split across 512 threads ----------------
// thread (e = t&255, hh = t>>8): all 4 gate cols of element e, k-half hh.
// hh=1 writes float4 partials to gbuf; hh=0 sums, does cell update, writes h.
__global__ __launch_bounds__(512, 2) void rnn_kernel(
    const unsigned int* __restrict__ whh_rf,
    const uint4* __restrict__ whh_lds,
    const uint4* __restrict__ whh_str,
    const half_t* __restrict__ xw,
    half_t* __restrict__ h_out,
    float* __restrict__ state_c,
    unsigned int* __restrict__ state_h)
{
    __shared__ uint4  lds_w[2 * KP_LDS * 256];   // 57344 B
    __shared__ float4 gbuf[256];                 // 4096 B
    __shared__ unsigned int hbuf[128];           // 512 B

    const int t    = threadIdx.x;
    const int e    = t & 255;
    const int hh   = t >> 8;
    const int lane = t & 63;
    const int b    = blockIdx.x;

    for (int i = t; i < 2 * KP_LDS * 256; i += 512) lds_w[i] = whh_lds[i];
    if (t < 128) hbuf[t] = state_h[b * 128 + t];
    float c = (hh == 0) ? state_c[b * 256 + e] : 0.0f;

    // register-resident Whh: k-pairs (hh*64 + 0..47) x 4 gate cols {e,256+e,512+e,768+e}
    unsigned int wreg[KP_RF][4];
    {
        const unsigned int* wrp = whh_rf + hh * (KP_RF * 1024) + e;
        #pragma unroll
        for (int pl = 0; pl < KP_RF; ++pl)
            #pragma unroll
            for (int j = 0; j < 4; ++j)
                wreg[pl][j] = wrp[pl * 1024 + j * 256];
    }
    __syncthreads();

    const half_t* xwp = xw + (size_t)b * T_CH * 1024 + e * 4;
    half_t* hop = h_out + (size_t)b * T_CH * 256 + e;
    const uint4* strp = whh_str + hh * (KP_STR * 256) + e;
    const uint4* ldp  = lds_w + hh * (KP_LDS * 256) + e;

    for (int step = 0; step < T_CH; ++step) {
        // h broadcast source: pairs hh*64 .. hh*64+63 (one LDS word per lane)
        unsigned int hv = hbuf[hh * 64 + lane];

        // issue long-latency loads early; consume late
        uint2 xv = {0, 0};
        if (hh == 0) xv = *(const uint2*)xwp;
        uint4 sq[KP_STR];
        #pragma unroll
        for (int sl = 0; sl < KP_STR; ++sl) sq[sl] = strp[sl * 256];

        float a0 = 0.f, a1 = 0.f, a2 = 0.f, a3 = 0.f;

        // RF part: local k-pairs 0..47
        #pragma unroll
        for (int pl = 0; pl < KP_RF; ++pl) {
            unsigned int s = rlane(hv, pl);
            a0 = dot2f(s, wreg[pl][0], a0);
            a1 = dot2f(s, wreg[pl][1], a1);
            a2 = dot2f(s, wreg[pl][2], a2);
            a3 = dot2f(s, wreg[pl][3], a3);
        }
        // streamed part: local k-pairs 55..63 (L2-hot, loop-invariant)
        #pragma unroll
        for (int sl = 0; sl < KP_STR; ++sl) {
            unsigned int s = rlane(hv, KP_RF + KP_LDS + sl);
            a0 = dot2f(s, sq[sl].x, a0);
            a1 = dot2f(s, sq[sl].y, a1);
            a2 = dot2f(s, sq[sl].z, a2);
            a3 = dot2f(s, sq[sl].w, a3);
        }
        // LDS part: local k-pairs 48..54
        #pragma unroll
        for (int ql = 0; ql < KP_LDS; ++ql) {
            uint4 q = ldp[ql * 256];
            unsigned int s = rlane(hv, KP_RF + ql);
            a0 = dot2f(s, q.x, a0);
            a1 = dot2f(s, q.y, a1);
            a2 = dot2f(s, q.z, a2);
            a3 = dot2f(s, q.w, a3);
        }

        if (hh) {
            float4 p; p.x = a0; p.y = a1; p.z = a2; p.w = a3;
            gbuf[e] = p;
        }
        __syncthreads();   // gbuf write -> read; hbuf read -> write

        if (hh == 0) {
            float4 p = gbuf[e];
            half2_t x0 = __builtin_bit_cast(half2_t, xv.x);
            half2_t x1 = __builtin_bit_cast(half2_t, xv.y);
            a0 += p.x + (float)x0.x;
            a1 += p.y + (float)x0.y;
            a2 += p.z + (float)x1.x;
            a3 += p.w + (float)x1.y;
            float ig = sigm(a0), fg = sigm(a1), gg = tanh_(a2), og = sigm(a3);
            c = fg * c + ig * gg;
            float hn = og * tanh_(c);
            half_t h16 = (half_t)hn;
            reinterpret_cast<half_t*>(hbuf)[e] = h16;
            *hop = h16;
        }
        xwp += 1024;
        hop += 256;
        __syncthreads();   // hbuf write -> next read; gbuf read -> next write
    }

    if (hh == 0) state_c[b * 256 + e] = c;
    if (t < 128) state_h[b * 128 + t] = hbuf[t];
}

// ---------------- launch ----------------
extern "C" void kernel_launch(void* const* d_in, const int* in_sizes, int n_in,
                              void* d_out, int out_size, void* d_ws, size_t ws_size,
                              hipStream_t stream) {
    const float* x    = (const float*)d_in[0];
    const float* c0   = (const float*)d_in[1];
    const float* h0   = (const float*)d_in[2];
    const float* Wih  = (const float*)d_in[3];
    const float* Whh  = (const float*)d_in[4];
    const float* bh   = (const float*)d_in[5];
    const float* Wout = (const float*)d_in[6];
    const float* bout = (const float*)d_in[7];

    char* ws = (char*)d_ws;
    half_t* xw             = (half_t*)(ws + OFF_XW);
    half_t* h_chunk        = (half_t*)(ws + OFF_H);
    half_t* wih_t          = (half_t*)(ws + OFF_WIH);
    half_t* wout_t         = (half_t*)(ws + OFF_WOUT);
    unsigned int* whh_rf   = (unsigned int*)(ws + OFF_WRF);
    unsigned int* whh_lds  = (unsigned int*)(ws + OFF_WLDS);
    unsigned int* whh_str  = (unsigned int*)(ws + OFF_WSTR);
    float* state_c         = (float*)(ws + OFF_SC);
    unsigned int* state_h  = (unsigned int*)(ws + OFF_SH);

    pack_kernel<<<512, 256, 0, stream>>>(Wih, Whh, Wout, c0, h0,
                                         wih_t, wout_t, whh_rf, whh_lds, whh_str,
                                         state_c, state_h);

    for (int ch = 0; ch < N_CHUNK; ++ch) {
        int chunk0 = ch * T_CH;
        gemm16<1, 0><<<dim3(CH_M / 128, G4 / 128), 256, 0, stream>>>(
            (const void*)x, wih_t, (void*)xw, bh, chunk0);
        rnn_kernel<<<B_SZ, 512, 0, stream>>>(whh_rf, (const uint4*)whh_lds,
                                             (const uint4*)whh_str, xw, h_chunk,
                                             state_c, state_h);
        gemm16<0, 1><<<dim3(CH_M / 128, H_SZ / 128), 256, 0, stream>>>(
            (const void*)h_chunk, wout_t, d_out, bout, chunk0);
    }
    (void)in_sizes; (void)n_in; (void)out_size; (void)ws_size;
}